// Round 5
// baseline (1015.975 us; speedup 1.0000x reference)
//
#include <hip/hip_runtime.h>

#define HO 62
#define WO 62
#define HW 3844               // HO*WO
#define CIN 32
#define COUT 64
#define KROW 288              // CIN*9 floats per (position, o) weight row
#define NJT 31                // j-tiles of 2 columns
#define NPH 8                 // phases: 4 input channels each
#define PHDW 36               // dwords per row per phase (4c * 9)
#define SLABDW 1152           // 32 rows * 36 dwords per wave per phase
#define NXCD 8

typedef const __attribute__((address_space(1))) void* gp_t;
typedef __attribute__((address_space(3))) void* lp_t;
typedef float f4   __attribute__((ext_vector_type(4)));              // 16B-aligned
typedef float f4a4 __attribute__((ext_vector_type(4), aligned(4)));  // 4B-aligned x loads

#define WF(k) wf[(k) >> 2][(k) & 3]   // static component pick -> stays in VGPRs

__global__ __launch_bounds__(256, 4)
void lc2d_kernel(const float* __restrict__ x,
                 const float* __restrict__ wgt,
                 float* __restrict__ out) {
    // per-wave-private double-buffered weight slabs: [wave][buf][32 rows * 36 dw].
    // Each wave's rows are read by no other wave -> ZERO barriers in the kernel;
    // phase sync is a counted s_waitcnt vmcnt(6) (next-phase DMAs stay in flight).
    __shared__ __align__(16) float lds[4][2][SLABDW];

    // bijective XCD chunk swizzle (nwg=1922, m204); j-tile fastest -> sequential
    // weight streaming per XCD, same-i x slab hot in that XCD's L2
    const int orig = blockIdx.x;
    const int nwg  = HO * NJT;
    const int qch  = nwg / NXCD, rch = nwg % NXCD;
    const int xcd  = orig % NXCD, cpos = orig / NXCD;
    const int wg   = ((xcd < rch) ? xcd * (qch + 1)
                                  : rch * (qch + 1) + (xcd - rch) * qch) + cpos;
    const int i  = wg / NJT;
    const int j0 = (wg % NJT) * 2;

    const int t      = threadIdx.x;
    const int w      = t >> 6;        // wave: (posoff = w>>1, ohalf = w&1)
    const int lane   = t & 63;
    const int o5     = lane & 31;     // o within half
    const int bh     = lane >> 5;     // batch octet
    const int posoff = w >> 1;
    const int ohalf  = w & 1;
    const int wsu    = __builtin_amdgcn_readfirstlane(w);
    const int pj     = i * WO + j0 + posoff;
    const int o      = ohalf * 32 + o5;

    // this wave's 32 contiguous weight rows
    const float* S = wgt + ((size_t)pj * COUT + ohalf * 32) * KROW;

    // per-lane DMA source offsets (dwords). LDS dest is linear (wave-uniform base +
    // lane*width); source is the matching strided slice. Verified identity:
    // U*4+m == (U/9)*36 + (U%9)*4 + m  -> LDS slab is packed [32][36].
    int g16[4], g4[2];
    #pragma unroll
    for (int q = 0; q < 4; ++q) {
        const int U = q * 64 + lane;                 // 16B units 0..255
        g16[q] = (U / 9) * KROW + (U % 9) * 4;
    }
    #pragma unroll
    for (int q = 0; q < 2; ++q) {
        const int d = 1024 + q * 64 + lane;          // dwords 1024..1151
        g4[q] = (d / PHDW) * KROW + (d % PHDW);
    }

    float* const lbase = &lds[wsu][0][0];

    // x base pointers (col j0, never OOB; component select handles posoff)
    const float* xq[8];
    #pragma unroll
    for (int bi = 0; bi < 8; ++bi)
        xq[bi] = x + (size_t)(bh * 8 + bi) * (CIN * 4096) + i * 64 + j0;

    float acc[8];
    #pragma unroll
    for (int bi = 0; bi < 8; ++bi) acc[bi] = 0.0f;

    // ---- prologue: stage phase 0 into buffer 0 ----
    #pragma unroll
    for (int q = 0; q < 4; ++q)
        __builtin_amdgcn_global_load_lds((gp_t)(S + g16[q]), (lp_t)(lbase + q * 256), 16, 0, 0);
    #pragma unroll
    for (int q = 0; q < 2; ++q)
        __builtin_amdgcn_global_load_lds((gp_t)(S + g4[q]), (lp_t)(lbase + 1024 + q * 64), 4, 0, 0);

    const float* wsrc = S + PHDW;
    int cur = 0;
    int xph = 0;

    #pragma unroll 1
    for (int p = 0; p < NPH; ++p) {
        __builtin_amdgcn_sched_barrier(0);
        // issue next-phase DMAs first (T14/T4): they ride across this phase's compute
        if (p + 1 < NPH) {
            float* nb = lbase + (cur ^ 1) * SLABDW;
            #pragma unroll
            for (int q = 0; q < 4; ++q)
                __builtin_amdgcn_global_load_lds((gp_t)(wsrc + g16[q]), (lp_t)(nb + q * 256), 16, 0, 0);
            #pragma unroll
            for (int q = 0; q < 2; ++q)
                __builtin_amdgcn_global_load_lds((gp_t)(wsrc + g4[q]), (lp_t)(nb + 1024 + q * 64), 4, 0, 0);
            wsrc += PHDW;
        }
        __builtin_amdgcn_sched_barrier(0);
        // counted wait: exactly the 6 just-issued DMAs may remain in flight;
        // everything older (this phase's slab, prior x loads) is retired.
        if (p + 1 < NPH) { asm volatile("s_waitcnt vmcnt(6)" ::: "memory"); }
        else             { asm volatile("s_waitcnt vmcnt(0)" ::: "memory"); }
        __builtin_amdgcn_sched_barrier(0);

        // this wave's 36 weights for 4 channels: 9x ds_read_b128
        // (lanes l and l+32 share o5 -> broadcast; within 32 lanes start-bank
        // spread over 8 groups -> cheap)
        const float* wb = lbase + cur * SLABDW + o5 * PHDW;
        f4 wf[9];
        #pragma unroll
        for (int g = 0; g < 9; ++g)
            wf[g] = *(const f4*)(wb + g * 4);

        // wave-uniform branch on position parity -> static x-component picks
        if (posoff == 0) {
            #pragma unroll
            for (int cc = 0; cc < 4; ++cc) {
                #pragma unroll
                for (int kh = 0; kh < 3; ++kh) {
                    const int xoff = xph + cc * 4096 + kh * 64;
                    const int k0 = cc * 9 + kh * 3;
                    #pragma unroll
                    for (int bi = 0; bi < 8; ++bi) {
                        const f4a4 xv = *(const f4a4*)(xq[bi] + xoff);
                        acc[bi] += WF(k0 + 0) * xv.x;
                        acc[bi] += WF(k0 + 1) * xv.y;
                        acc[bi] += WF(k0 + 2) * xv.z;
                    }
                }
            }
        } else {
            #pragma unroll
            for (int cc = 0; cc < 4; ++cc) {
                #pragma unroll
                for (int kh = 0; kh < 3; ++kh) {
                    const int xoff = xph + cc * 4096 + kh * 64;
                    const int k0 = cc * 9 + kh * 3;
                    #pragma unroll
                    for (int bi = 0; bi < 8; ++bi) {
                        const f4a4 xv = *(const f4a4*)(xq[bi] + xoff);
                        acc[bi] += WF(k0 + 0) * xv.y;
                        acc[bi] += WF(k0 + 1) * xv.z;
                        acc[bi] += WF(k0 + 2) * xv.w;
                    }
                }
            }
        }
        xph += 4 * 4096;
        cur ^= 1;
    }

    // ---- epilogue: sigmoid + scalar stores (one position per wave) ----
    #pragma unroll
    for (int bi = 0; bi < 8; ++bi) {
        const int b = bh * 8 + bi;
        out[(size_t)(b * COUT + o) * HW + pj] = 1.0f / (1.0f + __expf(-acc[bi]));
    }
}

extern "C" void kernel_launch(void* const* d_in, const int* in_sizes, int n_in,
                              void* d_out, int out_size, void* d_ws, size_t ws_size,
                              hipStream_t stream) {
    const float* x   = (const float*)d_in[0];
    const float* wgt = (const float*)d_in[1];
    float* out       = (float*)d_out;
    const int grid = HO * NJT;          // 1922 blocks * 4 waves
    lc2d_kernel<<<dim3(grid), dim3(256), 0, stream>>>(x, wgt, out);
}